// Round 4
// baseline (254.686 us; speedup 1.0000x reference)
//
#include <hip/hip_runtime.h>
#include <math.h>

#define BATCH 4096
#define NPTS  2048
#define THREADS 256

typedef float f32x4 __attribute__((ext_vector_type(4)));

__device__ __forceinline__ f32x4 ntload(const f32x4* p) {
    return __builtin_nontemporal_load(p);
}

// accumulate one point: h[c*3+d] += src_c * (m * tgt_d)
#define ACC(sx, sy, sz, tx, ty, tz, mm) do {                                   \
    float d0 = (mm) * (tx), d1 = (mm) * (ty), d2 = (mm) * (tz);                \
    h[0] = fmaf((sx), d0, h[0]); h[1] = fmaf((sx), d1, h[1]); h[2] = fmaf((sx), d2, h[2]); \
    h[3] = fmaf((sy), d0, h[3]); h[4] = fmaf((sy), d1, h[4]); h[5] = fmaf((sy), d2, h[5]); \
    h[6] = fmaf((sz), d0, h[6]); h[7] = fmaf((sz), d1, h[7]); h[8] = fmaf((sz), d2, h[8]); \
} while (0)

// Fused kernel: one block per batch (round-2 structure: solves from different
// blocks overlap naturally; round-3's intra-block pipeline made wave 0 a
// straggler and regressed).
//  Phase 1 (all 256 threads): H = src^T diag(mask) tgt, one burst of 14 NT
//    float4 loads per thread.
//  Phase 2 (thread 0): fp64 Jacobi + Kabsch, all compile-time-indexed so
//    state stays in VGPRs (round-1 lesson: runtime indices -> LDS scratch).
//
// KEY CHANGE vs round 2: __launch_bounds__(256, 8). Round 2 was latency-bound,
// not BW-bound (HBM 27%, VALU 25%, occ 51%): with only 4 resident blocks/CU
// the load-burst duty cycle was ~50% -- blocks spend half their life in the
// reduce/solve tail with no loads in flight. At 36 VGPR / 512 B LDS the HW can
// host 8 blocks/CU (2048 thr, VGPR cap 64 > 36); 8 phase-staggered blocks keep
// memory busy through every tail.
__global__ __launch_bounds__(THREADS, 8)
void fused_kernel(const float* __restrict__ src, const float* __restrict__ tgt,
                  const float* __restrict__ mask, float* __restrict__ out)
{
    const int b   = blockIdx.x;
    const int t   = threadIdx.x;           // group A: t, group B: t+256
    const f32x4* s4 = (const f32x4*)(src  + (size_t)b * (NPTS * 3));
    const f32x4* t4 = (const f32x4*)(tgt  + (size_t)b * (NPTS * 3));
    const f32x4* m4 = (const f32x4*)(mask + (size_t)b * NPTS);

    // ---- one burst: 14 independent NT loads ----
    f32x4 m0  = ntload(&m4[t]);
    f32x4 m1  = ntload(&m4[t + 256]);
    f32x4 sa0 = ntload(&s4[3 * t + 0]);
    f32x4 sb0 = ntload(&s4[3 * t + 1]);
    f32x4 sc0 = ntload(&s4[3 * t + 2]);
    f32x4 ta0 = ntload(&t4[3 * t + 0]);
    f32x4 tb0 = ntload(&t4[3 * t + 1]);
    f32x4 tc0 = ntload(&t4[3 * t + 2]);
    f32x4 sa1 = ntload(&s4[3 * (t + 256) + 0]);
    f32x4 sb1 = ntload(&s4[3 * (t + 256) + 1]);
    f32x4 sc1 = ntload(&s4[3 * (t + 256) + 2]);
    f32x4 ta1 = ntload(&t4[3 * (t + 256) + 0]);
    f32x4 tb1 = ntload(&t4[3 * (t + 256) + 1]);
    f32x4 tc1 = ntload(&t4[3 * (t + 256) + 2]);

    float h[9] = {0.f, 0.f, 0.f, 0.f, 0.f, 0.f, 0.f, 0.f, 0.f};
    ACC(sa0.x, sa0.y, sa0.z, ta0.x, ta0.y, ta0.z, m0.x);
    ACC(sa0.w, sb0.x, sb0.y, ta0.w, tb0.x, tb0.y, m0.y);
    ACC(sb0.z, sb0.w, sc0.x, tb0.z, tb0.w, tc0.x, m0.z);
    ACC(sc0.y, sc0.z, sc0.w, tc0.y, tc0.z, tc0.w, m0.w);
    ACC(sa1.x, sa1.y, sa1.z, ta1.x, ta1.y, ta1.z, m1.x);
    ACC(sa1.w, sb1.x, sb1.y, ta1.w, tb1.x, tb1.y, m1.y);
    ACC(sb1.z, sb1.w, sc1.x, tb1.z, tb1.w, tc1.x, m1.z);
    ACC(sc1.y, sc1.z, sc1.w, tc1.y, tc1.z, tc1.w, m1.w);

    // wave-64 butterfly reduction of the 9 accumulators
#pragma unroll
    for (int off = 32; off > 0; off >>= 1) {
#pragma unroll
        for (int i = 0; i < 9; ++i) h[i] += __shfl_down(h[i], off);
    }

    __shared__ float shred[THREADS / 64][9];
    const int wid  = t >> 6;
    const int lane = t & 63;
    if (lane == 0) {
#pragma unroll
        for (int i = 0; i < 9; ++i) shred[wid][i] = h[i];
    }
    __syncthreads();

    if (t != 0) return;

    // ---- Phase 2: single-thread fp64 Kabsch solve (all compile-time indexed) ----
    double H[3][3];
#pragma unroll
    for (int i = 0; i < 9; ++i)
        H[i / 3][i % 3] = (double)(shred[0][i] + shred[1][i] +
                                   shred[2][i] + shred[3][i]);

    double A[3][3];
#pragma unroll
    for (int i = 0; i < 3; ++i)
#pragma unroll
        for (int j = 0; j < 3; ++j)
            A[i][j] = H[0][i] * H[0][j] + H[1][i] * H[1][j] + H[2][i] * H[2][j];

    double V[3][3] = {{1, 0, 0}, {0, 1, 0}, {0, 0, 1}};

    for (int sweep = 0; sweep < 6; ++sweep) {
#pragma unroll
        for (int r = 0; r < 3; ++r) {
            // compile-time (p,q,k) per r: (0,1,2), (0,2,1), (1,2,0)
            const int p = (r == 2) ? 1 : 0;
            const int q = (r == 0) ? 1 : 2;
            const int k = (r == 0) ? 2 : ((r == 1) ? 1 : 0);
            double apq = A[p][q];
            if (fabs(apq) > 1e-300) {
                double theta = (A[q][q] - A[p][p]) / (2.0 * apq);
                double tt = 1.0 / (fabs(theta) + sqrt(theta * theta + 1.0));
                if (theta < 0.0) tt = -tt;
                double c = 1.0 / sqrt(tt * tt + 1.0);
                double s = tt * c;
                double app = A[p][p], aqq = A[q][q];
                A[p][p] = app - tt * apq;
                A[q][q] = aqq + tt * apq;
                A[p][q] = A[q][p] = 0.0;
                double akp = A[k][p], akq = A[k][q];
                A[k][p] = A[p][k] = c * akp - s * akq;
                A[k][q] = A[q][k] = s * akp + c * akq;
#pragma unroll
                for (int i = 0; i < 3; ++i) {
                    double vip = V[i][p], viq = V[i][q];
                    V[i][p] = c * vip - s * viq;
                    V[i][q] = s * vip + c * viq;
                }
            }
        }
    }

    // Branch-free eigen-column extraction (value selects only, no runtime
    // array indices -> stays in registers).
    const double d0 = A[0][0], d1 = A[1][1], d2 = A[2][2];
    const bool g01 = (d0 >= d1);
    const bool g02 = (d0 >= d2);
    const bool g12 = (d1 >= d2);
    const bool l0 = g01 && g02;        // column 0 is the largest
    const bool l1 = (!g01) && g12;     // column 1 is the largest

    double v0[3], v1[3];
#pragma unroll
    for (int i = 0; i < 3; ++i) {
        const double c0 = V[i][0], c1 = V[i][1], c2 = V[i][2];
        v0[i] = l0 ? c0 : (l1 ? c1 : c2);
        const double s_l0 = g12 ? c1 : c2;   // i0=0 -> i1 = d1>=d2 ? 1 : 2
        const double s_l1 = g02 ? c0 : c2;   // i0=1 -> i1 = d0>=d2 ? 0 : 2
        const double s_l2 = g01 ? c0 : c1;   // i0=2 -> i1 = d0>=d1 ? 0 : 1
        v1[i] = l0 ? s_l0 : (l1 ? s_l1 : s_l2);
    }

    double b0[3], b1[3];
#pragma unroll
    for (int r = 0; r < 3; ++r) {
        b0[r] = H[r][0] * v0[0] + H[r][1] * v0[1] + H[r][2] * v0[2];
        b1[r] = H[r][0] * v1[0] + H[r][1] * v1[1] + H[r][2] * v1[2];
    }
    double n0 = b0[0] * b0[0] + b0[1] * b0[1] + b0[2] * b0[2];
    double inv0 = 1.0 / sqrt(fmax(n0, 1e-300));
    double u0[3] = {b0[0] * inv0, b0[1] * inv0, b0[2] * inv0};
    double d01 = u0[0] * b1[0] + u0[1] * b1[1] + u0[2] * b1[2];
    double w[3] = {b1[0] - d01 * u0[0], b1[1] - d01 * u0[1], b1[2] - d01 * u0[2]};
    double nw = w[0] * w[0] + w[1] * w[1] + w[2] * w[2];
    double inv1 = 1.0 / sqrt(fmax(nw, 1e-300));
    double u1[3] = {w[0] * inv1, w[1] * inv1, w[2] * inv1};
    double u2[3] = {u0[1] * u1[2] - u0[2] * u1[1],
                    u0[2] * u1[0] - u0[0] * u1[2],
                    u0[0] * u1[1] - u0[1] * u1[0]};
    double vc2[3] = {v0[1] * v1[2] - v0[2] * v1[1],
                     v0[2] * v1[0] - v0[0] * v1[2],
                     v0[0] * v1[1] - v0[1] * v1[0]};

    float* o = out + (size_t)b * 9;
#pragma unroll
    for (int r = 0; r < 3; ++r)
#pragma unroll
        for (int c = 0; c < 3; ++c)
            o[r * 3 + c] = (float)(v0[r] * u0[c] + v1[r] * u1[c] + vc2[r] * u2[c]);
}

extern "C" void kernel_launch(void* const* d_in, const int* in_sizes, int n_in,
                              void* d_out, int out_size, void* d_ws, size_t ws_size,
                              hipStream_t stream) {
    const float* src  = (const float*)d_in[0];
    const float* tgt  = (const float*)d_in[1];
    // d_in[2] (kpt_src_mask) is unused by the reference
    const float* mask = (const float*)d_in[3];
    float* out = (float*)d_out;

    fused_kernel<<<BATCH, THREADS, 0, stream>>>(src, tgt, mask, out);
}

// Round 5
// 246.142 us; speedup vs baseline: 1.0347x; 1.0347x over previous
//
#include <hip/hip_runtime.h>
#include <math.h>

#define BATCH 4096
#define NPTS  2048
#define THREADS 256
#define BPB 4                    // batches per persistent block
#define GRID (BATCH / BPB)       // 1024 blocks = exactly 4 resident/CU, no churn

typedef float f32x4 __attribute__((ext_vector_type(4)));

__device__ __forceinline__ f32x4 ntload(const f32x4* p) {
    return __builtin_nontemporal_load(p);
}

// accumulate one point: h[c*3+d] += src_c * (m * tgt_d)
#define ACC(sx, sy, sz, tx, ty, tz, mm) do {                                   \
    float d0 = (mm) * (tx), d1 = (mm) * (ty), d2 = (mm) * (tz);                \
    h[0] = fmaf((sx), d0, h[0]); h[1] = fmaf((sx), d1, h[1]); h[2] = fmaf((sx), d2, h[2]); \
    h[3] = fmaf((sy), d0, h[3]); h[4] = fmaf((sy), d1, h[4]); h[5] = fmaf((sy), d2, h[5]); \
    h[6] = fmaf((sz), d0, h[6]); h[7] = fmaf((sz), d1, h[7]); h[8] = fmaf((sz), d2, h[8]); \
} while (0)

// One half-batch = one 4-point group per thread: mask quad + 3 src + 3 tgt quads.
#define DECL_HALF(P) f32x4 P##m, P##sa, P##sb, P##sc, P##ta, P##tb, P##tc;

#define LOAD_HALF(P, bb, g) do {                                               \
    const f32x4* s4_ = (const f32x4*)(src  + (size_t)(bb) * (NPTS * 3));       \
    const f32x4* t4_ = (const f32x4*)(tgt  + (size_t)(bb) * (NPTS * 3));       \
    const f32x4* m4_ = (const f32x4*)(mask + (size_t)(bb) * NPTS);             \
    const int g_ = (g);                                                        \
    P##m  = ntload(&m4_[g_]);                                                  \
    P##sa = ntload(&s4_[3 * g_ + 0]);                                          \
    P##sb = ntload(&s4_[3 * g_ + 1]);                                          \
    P##sc = ntload(&s4_[3 * g_ + 2]);                                          \
    P##ta = ntload(&t4_[3 * g_ + 0]);                                          \
    P##tb = ntload(&t4_[3 * g_ + 1]);                                          \
    P##tc = ntload(&t4_[3 * g_ + 2]);                                          \
} while (0)

#define FMA_HALF(P) do {                                                       \
    ACC(P##sa.x, P##sa.y, P##sa.z, P##ta.x, P##ta.y, P##ta.z, P##m.x);         \
    ACC(P##sa.w, P##sb.x, P##sb.y, P##ta.w, P##tb.x, P##tb.y, P##m.y);         \
    ACC(P##sb.z, P##sb.w, P##sc.x, P##tb.z, P##tb.w, P##tc.x, P##m.z);         \
    ACC(P##sc.y, P##sc.z, P##sc.w, P##tc.y, P##tc.z, P##tc.w, P##m.w);         \
} while (0)

// Persistent pipelined kernel, solves hoisted OUT of the streaming loop.
//  - 1024 blocks x 4 batches: every block resident for the whole kernel
//    (4 blocks/CU), no dispatch churn.
//  - Streaming loop is all-wave symmetric (round-3's failure: wave-0 solved
//    inside the loop, serializing every barrier on a 2us fp64 solve). Next
//    batch's A-half is issued BEFORE the current butterfly, so loads are in
//    flight across the reduce -- memory never drains.
//  - NO barriers inside the loop: each batch's wave-partials go to a distinct
//    LDS slot. One __syncthreads at the end.
//  - Tail: lanes 0-3 of wave 0 solve the 4 batches in SIMD-parallel (one
//    solve latency for all 4). Rotations are branch-free (selects) so lanes
//    stay converged. All solve arrays compile-time indexed (round-1 lesson);
//    H inputs come from LDS with runtime lane-dependent addresses (fine).
__global__ __launch_bounds__(THREADS, 4)
void fused_kernel(const float* __restrict__ src, const float* __restrict__ tgt,
                  const float* __restrict__ mask, float* __restrict__ out)
{
    const int t    = threadIdx.x;
    const int b0   = blockIdx.x * BPB;
    const int wid  = t >> 6;
    const int lane = t & 63;

    __shared__ float shred[BPB][THREADS / 64][9];   // 576 B

    DECL_HALF(A0) DECL_HALF(A1) DECL_HALF(B_)

#define ITER(CUR, NXT, jj, DO_PREF) do {                                       \
    LOAD_HALF(B_, b0 + (jj), t + 256);                                         \
    float h[9] = {0.f, 0.f, 0.f, 0.f, 0.f, 0.f, 0.f, 0.f, 0.f};               \
    FMA_HALF(CUR);                                                             \
    if (DO_PREF) { LOAD_HALF(NXT, b0 + (jj) + 1, t); }                         \
    FMA_HALF(B_);                                                              \
    _Pragma("unroll")                                                          \
    for (int off = 32; off > 0; off >>= 1) {                                   \
        _Pragma("unroll")                                                      \
        for (int i = 0; i < 9; ++i) h[i] += __shfl_down(h[i], off);            \
    }                                                                          \
    if (lane == 0) {                                                           \
        _Pragma("unroll")                                                      \
        for (int i = 0; i < 9; ++i) shred[jj][wid][i] = h[i];                  \
    }                                                                          \
} while (0)

    LOAD_HALF(A0, b0, t);      // prologue: A-half of batch 0
    ITER(A0, A1, 0, 1);
    ITER(A1, A0, 1, 1);
    ITER(A0, A1, 2, 1);
    ITER(A1, A0, 3, 0);
#undef ITER

    __syncthreads();

    if (t >= BPB) return;

    // ---- SIMD-parallel solve: lane t solves batch b0+t ----
    double H[3][3];
#pragma unroll
    for (int i = 0; i < 9; ++i)
        H[i / 3][i % 3] = (double)(shred[t][0][i] + shred[t][1][i] +
                                   shred[t][2][i] + shred[t][3][i]);

    double A[3][3];
#pragma unroll
    for (int i = 0; i < 3; ++i)
#pragma unroll
        for (int j = 0; j < 3; ++j)
            A[i][j] = H[0][i] * H[0][j] + H[1][i] * H[1][j] + H[2][i] * H[2][j];

    double V[3][3] = {{1, 0, 0}, {0, 1, 0}, {0, 0, 1}};

    for (int sweep = 0; sweep < 6; ++sweep) {
#pragma unroll
        for (int r = 0; r < 3; ++r) {
            // compile-time (p,q,k) per r: (0,1,2), (0,2,1), (1,2,0)
            const int p = (r == 2) ? 1 : 0;
            const int q = (r == 0) ? 1 : 2;
            const int k = (r == 0) ? 2 : ((r == 1) ? 1 : 0);
            // Branch-free rotation: when apq ~ 0 it degenerates to the
            // identity (c=1, s=0, tt=0) via selects -- lanes stay converged.
            double apq = A[p][q];
            const bool nz = fabs(apq) > 1e-300;
            double theta = (A[q][q] - A[p][p]) / (nz ? 2.0 * apq : 1.0);
            double tt = 1.0 / (fabs(theta) + sqrt(theta * theta + 1.0));
            tt = (theta < 0.0) ? -tt : tt;
            tt = nz ? tt : 0.0;
            double c = 1.0 / sqrt(tt * tt + 1.0);
            double s = tt * c;
            double app = A[p][p], aqq = A[q][q];
            A[p][p] = app - tt * apq;
            A[q][q] = aqq + tt * apq;
            A[p][q] = A[q][p] = 0.0;
            double akp = A[k][p], akq = A[k][q];
            A[k][p] = A[p][k] = c * akp - s * akq;
            A[k][q] = A[q][k] = s * akp + c * akq;
#pragma unroll
            for (int i = 0; i < 3; ++i) {
                double vip = V[i][p], viq = V[i][q];
                V[i][p] = c * vip - s * viq;
                V[i][q] = s * vip + c * viq;
            }
        }
    }

    // Branch-free eigen-column extraction (value selects only).
    const double d0 = A[0][0], d1 = A[1][1], d2 = A[2][2];
    const bool g01 = (d0 >= d1);
    const bool g02 = (d0 >= d2);
    const bool g12 = (d1 >= d2);
    const bool l0 = g01 && g02;
    const bool l1 = (!g01) && g12;

    double v0[3], v1[3];
#pragma unroll
    for (int i = 0; i < 3; ++i) {
        const double c0 = V[i][0], c1 = V[i][1], c2 = V[i][2];
        v0[i] = l0 ? c0 : (l1 ? c1 : c2);
        const double s_l0 = g12 ? c1 : c2;
        const double s_l1 = g02 ? c0 : c2;
        const double s_l2 = g01 ? c0 : c1;
        v1[i] = l0 ? s_l0 : (l1 ? s_l1 : s_l2);
    }

    double b0v[3], b1v[3];
#pragma unroll
    for (int r = 0; r < 3; ++r) {
        b0v[r] = H[r][0] * v0[0] + H[r][1] * v0[1] + H[r][2] * v0[2];
        b1v[r] = H[r][0] * v1[0] + H[r][1] * v1[1] + H[r][2] * v1[2];
    }
    double n0 = b0v[0] * b0v[0] + b0v[1] * b0v[1] + b0v[2] * b0v[2];
    double inv0 = 1.0 / sqrt(fmax(n0, 1e-300));
    double u0[3] = {b0v[0] * inv0, b0v[1] * inv0, b0v[2] * inv0};
    double d01 = u0[0] * b1v[0] + u0[1] * b1v[1] + u0[2] * b1v[2];
    double w[3] = {b1v[0] - d01 * u0[0], b1v[1] - d01 * u0[1], b1v[2] - d01 * u0[2]};
    double nw = w[0] * w[0] + w[1] * w[1] + w[2] * w[2];
    double inv1 = 1.0 / sqrt(fmax(nw, 1e-300));
    double u1[3] = {w[0] * inv1, w[1] * inv1, w[2] * inv1};
    double u2[3] = {u0[1] * u1[2] - u0[2] * u1[1],
                    u0[2] * u1[0] - u0[0] * u1[2],
                    u0[0] * u1[1] - u0[1] * u1[0]};
    double vc2[3] = {v0[1] * v1[2] - v0[2] * v1[1],
                     v0[2] * v1[0] - v0[0] * v1[2],
                     v0[0] * v1[1] - v0[1] * v1[0]};

    float* o = out + (size_t)(b0 + t) * 9;
#pragma unroll
    for (int r = 0; r < 3; ++r)
#pragma unroll
        for (int c = 0; c < 3; ++c)
            o[r * 3 + c] = (float)(v0[r] * u0[c] + v1[r] * u1[c] + vc2[r] * u2[c]);
}

extern "C" void kernel_launch(void* const* d_in, const int* in_sizes, int n_in,
                              void* d_out, int out_size, void* d_ws, size_t ws_size,
                              hipStream_t stream) {
    const float* src  = (const float*)d_in[0];
    const float* tgt  = (const float*)d_in[1];
    // d_in[2] (kpt_src_mask) is unused by the reference
    const float* mask = (const float*)d_in[3];
    float* out = (float*)d_out;

    fused_kernel<<<GRID, THREADS, 0, stream>>>(src, tgt, mask, out);
}

// Round 6
// 235.616 us; speedup vs baseline: 1.0809x; 1.0447x over previous
//
#include <hip/hip_runtime.h>
#include <math.h>

#define BATCH 4096
#define NPTS  2048
#define THREADS 256
#define BPB 4                    // batches per persistent block
#define GRID (BATCH / BPB)       // 1024 blocks = exactly 4 resident/CU

typedef float f32x4 __attribute__((ext_vector_type(4)));

__device__ __forceinline__ f32x4 ntload(const f32x4* p) {
    return __builtin_nontemporal_load(p);
}

// accumulate one point: h[c*3+d] += src_c * (m * tgt_d)
#define ACC(sx, sy, sz, tx, ty, tz, mm) do {                                   \
    float d0 = (mm) * (tx), d1 = (mm) * (ty), d2 = (mm) * (tz);                \
    h[0] = fmaf((sx), d0, h[0]); h[1] = fmaf((sx), d1, h[1]); h[2] = fmaf((sx), d2, h[2]); \
    h[3] = fmaf((sy), d0, h[3]); h[4] = fmaf((sy), d1, h[4]); h[5] = fmaf((sy), d2, h[5]); \
    h[6] = fmaf((sz), d0, h[6]); h[7] = fmaf((sz), d1, h[7]); h[8] = fmaf((sz), d2, h[8]); \
} while (0)

// Round-6 change: ALL global loads are lane-contiguous (16 B/lane). Round 5's
// per-point loads (lane stride 48/144 B, NT = L1-bypassed) made each wave64
// instruction touch ~64 quarter-used 64B lines -> ~4x line-request rate
// through TA/L2, capping delivery at ~3.9 TB/s (HBM 30%, VALU 11%, waves
// parked on vmcnt). Here each half-batch (1024 pts) is staged through LDS:
//   global (contiguous granule G) -> LDS transposed at (G%3)*256 + G/3
// so per-point READS sT[t], sT[256+t], sT[512+t] are lane-stride-1
// (canonical conflict-free b128); writes are ~3-way conflicted but off the
// critical path. A/B register sets double-buffer the staging so next-half
// loads are in flight across the consume phase. Point->thread ownership, FMA
// order, reduce and solve are bit-identical to round 5.
__global__ __launch_bounds__(THREADS, 4)
void fused_kernel(const float* __restrict__ src, const float* __restrict__ tgt,
                  const float* __restrict__ mask, float* __restrict__ out)
{
    const int t    = threadIdx.x;
    const int b0   = blockIdx.x * BPB;
    const int wid  = t >> 6;
    const int lane = t & 63;

    __shared__ f32x4 sT[768];                      // 12 KiB
    __shared__ f32x4 tT[768];                      // 12 KiB
    __shared__ f32x4 mL[256];                      //  4 KiB
    __shared__ float shred[BPB][THREADS / 64][9];  //  576 B

    const f32x4* s4 = (const f32x4*)src;
    const f32x4* t4 = (const f32x4*)tgt;
    const f32x4* m4 = (const f32x4*)mask;

    // Transposed write indices (constant across halves/batches):
    // global granule G in {t, t+256, t+512} -> LDS index (G%3)*256 + G/3.
    const int w0 = ((t      ) % 3) * 256 + (t      ) / 3;
    const int w1 = ((t + 256) % 3) * 256 + (t + 256) / 3;
    const int w2 = ((t + 512) % 3) * 256 + (t + 512) / 3;

    f32x4 As0, As1, As2, At0, At1, At2, Am;
    f32x4 Bs0, Bs1, Bs2, Bt0, Bt1, Bt2, Bm;

#define GLOAD(P, jj, hh) do {                                                  \
    const size_t sb_ = (size_t)(b0 + (jj)) * 1536 + (size_t)(hh) * 768;        \
    const size_t mb_ = (size_t)(b0 + (jj)) * 512  + (size_t)(hh) * 256;        \
    P##s0 = ntload(&s4[sb_ + t]);                                              \
    P##s1 = ntload(&s4[sb_ + t + 256]);                                        \
    P##s2 = ntload(&s4[sb_ + t + 512]);                                        \
    P##t0 = ntload(&t4[sb_ + t]);                                              \
    P##t1 = ntload(&t4[sb_ + t + 256]);                                        \
    P##t2 = ntload(&t4[sb_ + t + 512]);                                        \
    P##m  = ntload(&m4[mb_ + t]);                                              \
} while (0)

#define LWRITE(P) do {                                                         \
    sT[w0] = P##s0; sT[w1] = P##s1; sT[w2] = P##s2;                            \
    tT[w0] = P##t0; tT[w1] = P##t1; tT[w2] = P##t2;                            \
    mL[t]  = P##m;                                                             \
} while (0)

#define CONSUME() do {                                                         \
    f32x4 sa = sT[t], sbv = sT[256 + t], sc = sT[512 + t];                     \
    f32x4 ta = tT[t], tbv = tT[256 + t], tc = tT[512 + t];                     \
    f32x4 mv = mL[t];                                                          \
    ACC(sa.x,  sa.y,  sa.z,  ta.x,  ta.y,  ta.z,  mv.x);                       \
    ACC(sa.w,  sbv.x, sbv.y, ta.w,  tbv.x, tbv.y, mv.y);                       \
    ACC(sbv.z, sbv.w, sc.x,  tbv.z, tbv.w, tc.x,  mv.z);                       \
    ACC(sc.y,  sc.z,  sc.w,  tc.y,  tc.z,  tc.w,  mv.w);                       \
} while (0)

    float h[9];

#define ITER(CUR, NXT, jj, hh, PJ, PH, DO_PREF) do {                           \
    __syncthreads();              /* consumers of previous half done */        \
    LWRITE(CUR);                                                               \
    if (DO_PREF) { GLOAD(NXT, PJ, PH); }  /* in flight across consume */      \
    __syncthreads();              /* staged half visible */                    \
    if ((hh) == 0) {                                                           \
        _Pragma("unroll")                                                      \
        for (int i = 0; i < 9; ++i) h[i] = 0.f;                                \
    }                                                                          \
    CONSUME();                                                                 \
    if ((hh) == 1) {                                                           \
        _Pragma("unroll")                                                      \
        for (int off = 32; off > 0; off >>= 1) {                               \
            _Pragma("unroll")                                                  \
            for (int i = 0; i < 9; ++i) h[i] += __shfl_down(h[i], off);        \
        }                                                                      \
        if (lane == 0) {                                                       \
            _Pragma("unroll")                                                  \
            for (int i = 0; i < 9; ++i) shred[jj][wid][i] = h[i];              \
        }                                                                      \
    }                                                                          \
} while (0)

    GLOAD(A, 0, 0);              // prologue
    ITER(A, B, 0, 0, 0, 1, 1);
    ITER(B, A, 0, 1, 1, 0, 1);
    ITER(A, B, 1, 0, 1, 1, 1);
    ITER(B, A, 1, 1, 2, 0, 1);
    ITER(A, B, 2, 0, 2, 1, 1);
    ITER(B, A, 2, 1, 3, 0, 1);
    ITER(A, B, 3, 0, 3, 1, 1);
    ITER(B, A, 3, 1, 0, 0, 0);
#undef ITER
#undef CONSUME
#undef LWRITE
#undef GLOAD

    __syncthreads();

    if (t >= BPB) return;

    // ---- SIMD-parallel solve: lane t solves batch b0+t (round-5 tail) ----
    double H[3][3];
#pragma unroll
    for (int i = 0; i < 9; ++i)
        H[i / 3][i % 3] = (double)(shred[t][0][i] + shred[t][1][i] +
                                   shred[t][2][i] + shred[t][3][i]);

    double A[3][3];
#pragma unroll
    for (int i = 0; i < 3; ++i)
#pragma unroll
        for (int j = 0; j < 3; ++j)
            A[i][j] = H[0][i] * H[0][j] + H[1][i] * H[1][j] + H[2][i] * H[2][j];

    double V[3][3] = {{1, 0, 0}, {0, 1, 0}, {0, 0, 1}};

    for (int sweep = 0; sweep < 6; ++sweep) {
#pragma unroll
        for (int r = 0; r < 3; ++r) {
            // compile-time (p,q,k) per r: (0,1,2), (0,2,1), (1,2,0)
            const int p = (r == 2) ? 1 : 0;
            const int q = (r == 0) ? 1 : 2;
            const int k = (r == 0) ? 2 : ((r == 1) ? 1 : 0);
            // Branch-free rotation (selects) so the 4 solving lanes converge.
            double apq = A[p][q];
            const bool nz = fabs(apq) > 1e-300;
            double theta = (A[q][q] - A[p][p]) / (nz ? 2.0 * apq : 1.0);
            double tt = 1.0 / (fabs(theta) + sqrt(theta * theta + 1.0));
            tt = (theta < 0.0) ? -tt : tt;
            tt = nz ? tt : 0.0;
            double c = 1.0 / sqrt(tt * tt + 1.0);
            double s = tt * c;
            double app = A[p][p], aqq = A[q][q];
            A[p][p] = app - tt * apq;
            A[q][q] = aqq + tt * apq;
            A[p][q] = A[q][p] = 0.0;
            double akp = A[k][p], akq = A[k][q];
            A[k][p] = A[p][k] = c * akp - s * akq;
            A[k][q] = A[q][k] = s * akp + c * akq;
#pragma unroll
            for (int i = 0; i < 3; ++i) {
                double vip = V[i][p], viq = V[i][q];
                V[i][p] = c * vip - s * viq;
                V[i][q] = s * vip + c * viq;
            }
        }
    }

    // Branch-free eigen-column extraction (value selects only).
    const double d0 = A[0][0], d1 = A[1][1], d2 = A[2][2];
    const bool g01 = (d0 >= d1);
    const bool g02 = (d0 >= d2);
    const bool g12 = (d1 >= d2);
    const bool l0 = g01 && g02;
    const bool l1 = (!g01) && g12;

    double v0[3], v1[3];
#pragma unroll
    for (int i = 0; i < 3; ++i) {
        const double c0 = V[i][0], c1 = V[i][1], c2 = V[i][2];
        v0[i] = l0 ? c0 : (l1 ? c1 : c2);
        const double s_l0 = g12 ? c1 : c2;
        const double s_l1 = g02 ? c0 : c2;
        const double s_l2 = g01 ? c0 : c1;
        v1[i] = l0 ? s_l0 : (l1 ? s_l1 : s_l2);
    }

    double b0v[3], b1v[3];
#pragma unroll
    for (int r = 0; r < 3; ++r) {
        b0v[r] = H[r][0] * v0[0] + H[r][1] * v0[1] + H[r][2] * v0[2];
        b1v[r] = H[r][0] * v1[0] + H[r][1] * v1[1] + H[r][2] * v1[2];
    }
    double n0 = b0v[0] * b0v[0] + b0v[1] * b0v[1] + b0v[2] * b0v[2];
    double inv0 = 1.0 / sqrt(fmax(n0, 1e-300));
    double u0[3] = {b0v[0] * inv0, b0v[1] * inv0, b0v[2] * inv0};
    double d01 = u0[0] * b1v[0] + u0[1] * b1v[1] + u0[2] * b1v[2];
    double w[3] = {b1v[0] - d01 * u0[0], b1v[1] - d01 * u0[1], b1v[2] - d01 * u0[2]};
    double nw = w[0] * w[0] + w[1] * w[1] + w[2] * w[2];
    double inv1 = 1.0 / sqrt(fmax(nw, 1e-300));
    double u1[3] = {w[0] * inv1, w[1] * inv1, w[2] * inv1};
    double u2[3] = {u0[1] * u1[2] - u0[2] * u1[1],
                    u0[2] * u1[0] - u0[0] * u1[2],
                    u0[0] * u1[1] - u0[1] * u1[0]};
    double vc2[3] = {v0[1] * v1[2] - v0[2] * v1[1],
                     v0[2] * v1[0] - v0[0] * v1[2],
                     v0[0] * v1[1] - v0[1] * v1[0]};

    float* o = out + (size_t)(b0 + t) * 9;
#pragma unroll
    for (int r = 0; r < 3; ++r)
#pragma unroll
        for (int c = 0; c < 3; ++c)
            o[r * 3 + c] = (float)(v0[r] * u0[c] + v1[r] * u1[c] + vc2[r] * u2[c]);
}

extern "C" void kernel_launch(void* const* d_in, const int* in_sizes, int n_in,
                              void* d_out, int out_size, void* d_ws, size_t ws_size,
                              hipStream_t stream) {
    const float* src  = (const float*)d_in[0];
    const float* tgt  = (const float*)d_in[1];
    // d_in[2] (kpt_src_mask) is unused by the reference
    const float* mask = (const float*)d_in[3];
    float* out = (float*)d_out;

    fused_kernel<<<GRID, THREADS, 0, stream>>>(src, tgt, mask, out);
}